// Round 2
// baseline (174.452 us; speedup 1.0000x reference)
//
#include <hip/hip_runtime.h>

#define N_NODES_C   524288
#define N_EDGES_C   786432
#define NUM_GRAPHS_C 8192
#define NT 16          // NUM_NODE_TYPES
#define NODE_DIM_C 256
#define EDGE_DIM_C 128
#define HDIM 384       // NODE_DIM + EDGE_DIM
#define KC 48          // folded inner dim: 16 (node) + 32 (edge)

// R12: XCD-sliced edge gather. h_node = 32 MiB = 8 x 4 MiB = one L2 per XCD.
// Each graph gets 8 edge waves, one per node-slice (slice = idx>>16); wave's
// block is placed so blk%8 == slice == XCD (m09 heuristic). Each XCD then only
// gathers rows from its own 4-MiB slice -> L2-resident after first touch.
// Correctness is mapping-independent (slices partition nodes exactly); only
// locality rides on blk%8==XCD. Partial sums merge via atomicAdd into em
// (zeroed by k0). Segment bounds precomputed in k0 (O(E) boundary detect)
// instead of 20-level dependent binary searches in every wave.
#define FOLD_BLOCKS  72            // ceil(KC*HDIM / 256)
#define EDGE_BLOCKS  16384         // 8 slices x 2048; 4 waves/blk, wave=(g,slice)
#define NODE_BLOCKS  2048
#define EDGE_BASE    FOLD_BLOCKS   // 72 % 8 == 0 so (blk-EDGE_BASE)&7 == blk&7
#define NODE_BASE    (FOLD_BLOCKS + EDGE_BLOCKS)
#define TOTAL_BLOCKS (FOLD_BLOCKS + EDGE_BLOCKS + NODE_BLOCKS)
#define K0_BLOCKS    3072          // 786432 threads, covers E and N and em-zero

// ---------------- workspace layout (bytes) ----------------
#define WS_NM    0                  // float[8192*16]   (node means)
#define WS_EM    524288             // float[8192*32]   (edge sums -> means)
#define WS_WC    1572864            // float[48*384]    (folded weights)
#define WS_ES    1646592            // int[8193]        (edge segment starts)
#define WS_NS    1679364            // int[8193]        (node segment starts)

__device__ __forceinline__ void f4_add(float4& a, const float4 v) {
    a.x += v.x; a.y += v.y; a.z += v.z; a.w += v.w;
}

__device__ __forceinline__ void f4_shfl_xor_add(float4& a, int mask) {
    a.x += __shfl_xor(a.x, mask, 64);
    a.y += __shfl_xor(a.y, mask, 64);
    a.z += __shfl_xor(a.z, mask, 64);
    a.w += __shfl_xor(a.w, mask, 64);
}

// k0: segment starts via boundary detection (batch arrays are sorted) + zero em.
// estart[g] = first i with bedge[i] >= g; estart[NUM_GRAPHS] = E. Same for nodes.
__global__ __launch_bounds__(256) void k0_prep(
    const int* __restrict__ bnode, const int* __restrict__ bedge,
    int* __restrict__ estart, int* __restrict__ nstart, float* __restrict__ em) {
    int i = blockIdx.x * 256 + threadIdx.x;
    if (i < NUM_GRAPHS_C * 32) em[i] = 0.f;
    if (i < N_EDGES_C) {
        int g0 = bedge[i];
        int hi = (i + 1 < N_EDGES_C) ? bedge[i + 1] : NUM_GRAPHS_C;
        if (i == 0) for (int g = 0; g <= g0; ++g) estart[g] = 0;
        for (int g = g0 + 1; g <= hi; ++g) estart[g] = i + 1;
    }
    if (i < N_NODES_C) {
        int g0 = bnode[i];
        int hi = (i + 1 < N_NODES_C) ? bnode[i + 1] : NUM_GRAPHS_C;
        if (i == 0) for (int g = 0; g <= g0; ++g) nstart[g] = 0;
        for (int g = g0 + 1; g <= hi; ++g) nstart[g] = i + 1;
    }
}

// KM mega-kernel:
//  blocks [0,72):              Wc[k][j] = embedder_row(k) . W1 block (unroll 16)
//  blocks [EDGE_BASE,+16384):  edge partial means, wave = (graph, slice).
//     lane = eo(0..7)*8 + p*4 + quad; quad shares a 64-B row (R0-verified
//     2-chain, stride 16, 1-deep idx prefetch); row load predicated on
//     idx>>16 == slice; eo-reduce; inv-scaled atomicAdd into em.
//  blocks [NODE_BASE,+2048):   node means, wave/graph, fully-coalesced float4.
__global__ __launch_bounds__(256) void km_mega(
    const float* __restrict__ h_node,
    const int* __restrict__ esrc, const int* __restrict__ edst,
    const int* __restrict__ estart, const int* __restrict__ nstart,
    const float* __restrict__ Wn, const float* __restrict__ We,
    const float* __restrict__ W1,
    float* __restrict__ nm, float* __restrict__ em, float* __restrict__ Wc) {
    int blk  = blockIdx.x;
    int wave = threadIdx.x >> 6;
    int lane = threadIdx.x & 63;
    const float4* h4 = (const float4*)h_node;
    const float4 z4 = make_float4(0.f, 0.f, 0.f, 0.f);

    if (blk < FOLD_BLOCKS) {
        // ---- weight fold ----
        int o = blk * 256 + threadIdx.x;        // 0..18431 (= KC*HDIM)
        if (o >= KC * HDIM) return;
        int k = o / HDIM, j = o % HDIM;
        float acc = 0.f;
        if (k < NT) {
            const float* wr = &Wn[k * NODE_DIM_C];
            #pragma unroll 16
            for (int kk = 0; kk < NODE_DIM_C; ++kk)
                acc = fmaf(wr[kk], W1[(size_t)kk * HDIM + j], acc);
        } else {
            const float* wr = &We[(k - NT) * EDGE_DIM_C];
            #pragma unroll 16
            for (int kk = 0; kk < EDGE_DIM_C; ++kk)
                acc = fmaf(wr[kk], W1[(size_t)(NODE_DIM_C + kk) * HDIM + j], acc);
        }
        Wc[o] = acc;
    } else if (blk < NODE_BASE) {
        // ---- edge partial means (slice-filtered gather) ----
        int eb    = blk - EDGE_BASE;
        int slice = eb & 7;                     // == blk%8 == XCD (heuristic)
        int g     = (eb >> 3) * 4 + wave;
        int s = estart[g], e = estart[g + 1];
        int eo   = lane >> 3;          // 0..7 edge slot
        int p    = (lane >> 2) & 1;    // 0=src 1=dst
        int quad = lane & 3;           // 16 B quarter of the 64-B row
        const int* __restrict__ idxp = p ? edst : esrc;
        float4 accA = z4, accB = z4;
        int iA = s + eo, iB = iA + 8;
        int nxA = (iA < e) ? idxp[iA] : -1;
        int nxB = (iB < e) ? idxp[iB] : -1;
        while (nxB >= 0) {             // nxB valid implies nxA valid (iA < iB)
            int idxA = nxA, idxB = nxB;
            iA += 16; iB += 16;
            nxA = (iA < e) ? idxp[iA] : -1;   // prefetch next pair (independent)
            nxB = (iB < e) ? idxp[iB] : -1;
            if ((idxA >> 16) == slice) f4_add(accA, h4[(size_t)idxA * 4 + quad]);
            if ((idxB >> 16) == slice) f4_add(accB, h4[(size_t)idxB * 4 + quad]);
        }
        if (nxA >= 0 && (nxA >> 16) == slice)   // at most one pending A element
            f4_add(accA, h4[(size_t)nxA * 4 + quad]);
        f4_add(accA, accB);
        // reduce over eo (lane bits 3..5)
        f4_shfl_xor_add(accA, 8);
        f4_shfl_xor_add(accA, 16);
        f4_shfl_xor_add(accA, 32);
        if (eo == 0) {
            // scale partial by inv(cnt) so the 8 slice-partials sum to the mean
            float inv = 1.f / fmaxf((float)(e - s), 1.f);
            // em row = 32 floats: quads 0..3 = src half, 4..7 = dst half
            float* dst = &em[(size_t)g * 32 + p * 16 + quad * 4];
            atomicAdd(dst + 0, accA.x * inv);
            atomicAdd(dst + 1, accA.y * inv);
            atomicAdd(dst + 2, accA.z * inv);
            atomicAdd(dst + 3, accA.w * inv);
        }
    } else {
        // ---- node means ----
        int g = (blk - NODE_BASE) * 4 + wave;
        int s = nstart[g], e = nstart[g + 1];
        int row_off = lane >> 2;   // 0..15
        int quad    = lane & 3;    // 0..3
        float4 a0 = z4, a1 = z4;
        int i = s + row_off;
        for (; i + 16 < e; i += 32) {
            float4 v0 = h4[(size_t)i * 4 + quad];
            float4 v1 = h4[(size_t)(i + 16) * 4 + quad];
            f4_add(a0, v0);
            f4_add(a1, v1);
        }
        if (i < e) f4_add(a0, h4[(size_t)i * 4 + quad]);
        f4_add(a0, a1);
        f4_shfl_xor_add(a0, 4);
        f4_shfl_xor_add(a0, 8);
        f4_shfl_xor_add(a0, 16);
        f4_shfl_xor_add(a0, 32);
        if (row_off == 0) {
            float inv = 1.f / fmaxf((float)(e - s), 1.f);
            ((float4*)nm)[(size_t)g * 4 + quad] =
                make_float4(a0.x * inv, a0.y * inv, a0.z * inv, a0.w * inv);
        }
    }
}

// K3: fused MLP.  pred[g] = relu(f[g] @ Wc + b1) . W2 + b2,  f = [nm | em] (48)
// 384 threads (thread owns column j of Wc in registers), 16 graphs / block.
#define GPB 16
__global__ __launch_bounds__(HDIM) void k3_mlp(
    const float* __restrict__ nm, const float* __restrict__ em,
    const float* __restrict__ Wc, const float* __restrict__ b1,
    const float* __restrict__ W2, const float* __restrict__ b2,
    float* __restrict__ pred) {
    int j = threadIdx.x;
    float wc[KC];
    #pragma unroll
    for (int k = 0; k < KC; ++k) wc[k] = Wc[k * HDIM + j];
    float b1j = b1[j], w2j = W2[j], b20 = b2[0];

    __shared__ float fs[GPB][KC];
    __shared__ float part[GPB][6];
    int g0 = blockIdx.x * GPB;
    #pragma unroll
    for (int t = j; t < GPB * KC; t += HDIM) {
        int g = t / KC, k = t % KC;
        fs[g][k] = (k < NT) ? nm[(size_t)(g0 + g) * NT + k]
                            : em[(size_t)(g0 + g) * 32 + (k - NT)];
    }
    __syncthreads();

    int wave = j >> 6, lane = j & 63;
    for (int g = 0; g < GPB; ++g) {
        float z = b1j;
        #pragma unroll
        for (int k = 0; k < KC; ++k) z = fmaf(fs[g][k], wc[k], z);
        z = fmaxf(z, 0.f);
        float p = z * w2j;
        #pragma unroll
        for (int off = 32; off > 0; off >>= 1) p += __shfl_down(p, off, 64);
        if (lane == 0) part[g][wave] = p;
    }
    __syncthreads();
    if (j < GPB) {
        float sacc = b20;
        #pragma unroll
        for (int w = 0; w < 6; ++w) sacc += part[j][w];
        pred[g0 + j] = sacc;
    }
}

extern "C" void kernel_launch(void* const* d_in, const int* in_sizes, int n_in,
                              void* d_out, int out_size, void* d_ws, size_t ws_size,
                              hipStream_t stream) {
    const float* h_node     = (const float*)d_in[0];
    // d_in[1] = pos_node (unused)
    const int*   batch_node = (const int*)d_in[2];
    const int*   edge_index = (const int*)d_in[3];   // [2, E] row-major
    const int*   batch_edge = (const int*)d_in[4];
    const float* W_node     = (const float*)d_in[5];
    const float* W_edge     = (const float*)d_in[6];
    const float* W1         = (const float*)d_in[7];
    const float* b1         = (const float*)d_in[8];
    const float* W2         = (const float*)d_in[9];
    const float* b2         = (const float*)d_in[10];
    float* pred = (float*)d_out;

    char* ws = (char*)d_ws;
    float* nm     = (float*)(ws + WS_NM);
    float* em     = (float*)(ws + WS_EM);
    float* Wc     = (float*)(ws + WS_WC);
    int*   estart = (int*)(ws + WS_ES);
    int*   nstart = (int*)(ws + WS_NS);

    const int* esrc = edge_index;
    const int* edst = edge_index + N_EDGES_C;

    // k0: segment bounds + em zero (stream-ordered before km)
    k0_prep<<<K0_BLOCKS, 256, 0, stream>>>(batch_node, batch_edge, estart, nstart, em);
    // KM: fold (72) + sliced edge partials (16384) + node means (2048)
    km_mega<<<TOTAL_BLOCKS, 256, 0, stream>>>(
        h_node, esrc, edst, estart, nstart, W_node, W_edge, W1, nm, em, Wc);
    // K3: fused folded MLP
    k3_mlp<<<NUM_GRAPHS_C / GPB, HDIM, 0, stream>>>(nm, em, Wc, b1, W2, b2, pred);
}